// Round 1
// baseline (372.324 us; speedup 1.0000x reference)
//
#include <hip/hip_runtime.h>
#include <hip/hip_bf16.h>

// Problem constants (derived at launch from in_sizes, but layout is fixed):
// IN_DIM=128, H=8, D=16, H*D=128.

#define GEMM_BN 64

// ---------------------------------------------------------------------------
// Fused QKV GEMM: Y = h @ W + b for three weights. fp32 vector ALU.
// Block: 256 threads, 64 rows. LDS: hT[k][r] 32KB + wS[k][c] 32KB = 64KB.
// ---------------------------------------------------------------------------
__global__ __launch_bounds__(256) void qkv_gemm(
    const float* __restrict__ h,
    const float* __restrict__ W0, const float* __restrict__ b0,
    const float* __restrict__ W1, const float* __restrict__ b1,
    const float* __restrict__ W2, const float* __restrict__ b2,
    float* __restrict__ Y0, float* __restrict__ Y1, float* __restrict__ Y2,
    int n)
{
    __shared__ float hT[128][GEMM_BN];  // [k][row] transposed h tile
    __shared__ float wS[128][64];       // [k][col] weight half-tile

    const int tid  = threadIdx.x;
    const int row0 = blockIdx.x * GEMM_BN;

    // Stage hT: thread covers (r = tid&63, k-range = (tid>>6)*32 .. +32)
    {
        const int r = tid & 63, kq = tid >> 6;
        const int row = row0 + r;
        if (row < n) {
            const float* hp = h + (size_t)row * 128 + kq * 32;
#pragma unroll
            for (int j = 0; j < 8; ++j) {
                float4 v = *(const float4*)(hp + j * 4);
                int k = kq * 32 + j * 4;
                hT[k + 0][r] = v.x; hT[k + 1][r] = v.y;
                hT[k + 2][r] = v.z; hT[k + 3][r] = v.w;
            }
        } else {
#pragma unroll
            for (int j = 0; j < 8; ++j) {
                int k = kq * 32 + j * 4;
                hT[k + 0][r] = 0.f; hT[k + 1][r] = 0.f;
                hT[k + 2][r] = 0.f; hT[k + 3][r] = 0.f;
            }
        }
    }

    const float* Ws[3] = {W0, W1, W2};
    const float* bs[3] = {b0, b1, b2};
    float*       Ys[3] = {Y0, Y1, Y2};

    const int tc = tid & 15;   // col group: cols tc*4..tc*4+3 within the half
    const int tr = tid >> 4;   // row group: rows tr*4..tr*4+3

    for (int w = 0; w < 3; ++w) {
        for (int ch = 0; ch < 2; ++ch) {
            __syncthreads();   // protects hT stage (first iter) / prev compute
            // Stage wS[k][c] = W[k][ch*64 + c]; coalesced float4 loads.
            for (int t = tid; t < 128 * 16; t += 256) {
                int k = t >> 4, c4 = (t & 15) * 4;
                *(float4*)&wS[k][c4] =
                    *(const float4*)(Ws[w] + (size_t)k * 128 + ch * 64 + c4);
            }
            __syncthreads();

            float acc[4][4];
            float4 bvv = *(const float4*)(bs[w] + ch * 64 + tc * 4);
#pragma unroll
            for (int i = 0; i < 4; ++i) {
                acc[i][0] = bvv.x; acc[i][1] = bvv.y;
                acc[i][2] = bvv.z; acc[i][3] = bvv.w;
            }

#pragma unroll 8
            for (int k = 0; k < 128; ++k) {
                float4 a = *(const float4*)&hT[k][tr * 4];
                float4 b = *(const float4*)&wS[k][tc * 4];
                float ar[4] = {a.x, a.y, a.z, a.w};
                float br[4] = {b.x, b.y, b.z, b.w};
#pragma unroll
                for (int i = 0; i < 4; ++i)
#pragma unroll
                    for (int j = 0; j < 4; ++j)
                        acc[i][j] = fmaf(ar[i], br[j], acc[i][j]);
            }

            float* Y = Ys[w];
#pragma unroll
            for (int i = 0; i < 4; ++i) {
                int row = row0 + tr * 4 + i;
                if (row < n) {
                    *(float4*)(Y + (size_t)row * 128 + ch * 64 + tc * 4) =
                        make_float4(acc[i][0], acc[i][1], acc[i][2], acc[i][3]);
                }
            }
        }
    }
}

// ---------------------------------------------------------------------------
// CSR build: histogram -> hierarchical exclusive scan -> fill
// ---------------------------------------------------------------------------
__global__ void hist_kernel(const int* __restrict__ dst, int* __restrict__ counts, int e) {
    int i = blockIdx.x * blockDim.x + threadIdx.x;
    if (i < e) atomicAdd(&counts[dst[i]], 1);
}

__global__ void scan_block_sums(const int* __restrict__ counts, int* __restrict__ bsums, int nelem) {
    __shared__ int red[4];
    int i = blockIdx.x * 256 + threadIdx.x;
    int v = (i < nelem) ? counts[i] : 0;
#pragma unroll
    for (int o = 32; o > 0; o >>= 1) v += __shfl_down(v, o, 64);
    if ((threadIdx.x & 63) == 0) red[threadIdx.x >> 6] = v;
    __syncthreads();
    if (threadIdx.x == 0) bsums[blockIdx.x] = red[0] + red[1] + red[2] + red[3];
}

__global__ void scan_exclusive_small(int* __restrict__ bsums, int nb) {
    __shared__ int tmp[256];
    int t = threadIdx.x;
    int v = (t < nb) ? bsums[t] : 0;
    tmp[t] = v;
    __syncthreads();
    for (int o = 1; o < 256; o <<= 1) {
        int u = (t >= o) ? tmp[t - o] : 0;
        __syncthreads();
        tmp[t] += u;
        __syncthreads();
    }
    if (t < nb) bsums[t] = tmp[t] - v;  // exclusive
}

__global__ void scan_final(const int* __restrict__ counts, const int* __restrict__ bsums,
                           int* __restrict__ offsets, int nelem, int e) {
    __shared__ int tmp[256];
    int t = threadIdx.x;
    int i = blockIdx.x * 256 + t;
    int v = (i < nelem) ? counts[i] : 0;
    tmp[t] = v;
    __syncthreads();
    for (int o = 1; o < 256; o <<= 1) {
        int u = (t >= o) ? tmp[t - o] : 0;
        __syncthreads();
        tmp[t] += u;
        __syncthreads();
    }
    if (i < nelem) offsets[i] = bsums[blockIdx.x] + tmp[t] - v;
    if (i == 0 && blockIdx.x == 0) offsets[nelem] = e;
}

__global__ void fill_kernel(const int* __restrict__ src, const int* __restrict__ dst,
                            const int* __restrict__ offsets, int* __restrict__ cursor,
                            int* __restrict__ srcSorted, int e) {
    int i = blockIdx.x * blockDim.x + threadIdx.x;
    if (i < e) {
        int d = dst[i];
        int pos = offsets[d] + atomicAdd(&cursor[d], 1);
        srcSorted[pos] = src[i];
    }
}

// ---------------------------------------------------------------------------
// Main gather kernel: one 16-lane group per (node, head).
// Scores are clamped to [-5,5] BEFORE softmax => exp(s) in [6.7e-3, 148.4],
// so the segment-max subtraction is unnecessary (softmax shift-invariance).
// ---------------------------------------------------------------------------
__global__ __launch_bounds__(256) void mha_edge(
    const float* __restrict__ Q, const float* __restrict__ K, const float* __restrict__ V,
    const int* __restrict__ offsets, const int* __restrict__ srcSorted,
    float* __restrict__ out, int n)
{
    int g = (blockIdx.x * blockDim.x + threadIdx.x) >> 4;  // group id
    int lane = threadIdx.x & 15;
    if (g >= n * 8) return;
    int node = g >> 3, head = g & 7;
    int base = head * 16 + lane;

    float q = Q[(size_t)node * 128 + base];
    int beg = offsets[node], end = offsets[node + 1];

    float l = 0.f, acc = 0.f;
    for (int j = beg; j < end; ++j) {
        int s = srcSorted[j];
        float kv = K[(size_t)s * 128 + base];
        float vv = V[(size_t)s * 128 + base];
        float prod = kv * q;
        prod += __shfl_xor(prod, 1, 16);
        prod += __shfl_xor(prod, 2, 16);
        prod += __shfl_xor(prod, 4, 16);
        prod += __shfl_xor(prod, 8, 16);
        float sc = prod * 0.25f;             // / sqrt(16)
        sc = fminf(5.f, fmaxf(-5.f, sc));    // clip
        float p = __expf(sc);
        l += p;
        acc = fmaf(p, vv, acc);
    }
    out[(size_t)node * 128 + base] = (l > 0.f) ? acc / l : 0.f;
}

// ---------------------------------------------------------------------------
extern "C" void kernel_launch(void* const* d_in, const int* in_sizes, int n_in,
                              void* d_out, int out_size, void* d_ws, size_t ws_size,
                              hipStream_t stream) {
    const float* h  = (const float*)d_in[0];
    const float* Wq = (const float*)d_in[1];
    const float* bq = (const float*)d_in[2];
    const float* Wk = (const float*)d_in[3];
    const float* bk = (const float*)d_in[4];
    const float* Wv = (const float*)d_in[5];
    const float* bv = (const float*)d_in[6];
    const int*   src = (const int*)d_in[7];
    const int*   dst = (const int*)d_in[8];
    float* out = (float*)d_out;

    const int n = in_sizes[0] / 128;
    const int e = in_sizes[7];
    const int nb = (n + 255) / 256;  // scan blocks (must be <= 256)

    char* ws = (char*)d_ws;
    size_t off = 0;
    auto alloc = [&](size_t bytes) {
        char* p = ws + off;
        off = (off + bytes + 255) & ~(size_t)255;
        return p;
    };
    float* Q        = (float*)alloc((size_t)n * 128 * sizeof(float));
    float* K        = (float*)alloc((size_t)n * 128 * sizeof(float));
    float* V        = (float*)alloc((size_t)n * 128 * sizeof(float));
    int*   counts   = (int*)alloc((size_t)n * sizeof(int));
    int*   offsets  = (int*)alloc((size_t)(n + 1) * sizeof(int));
    int*   bsums    = (int*)alloc((size_t)nb * sizeof(int));
    int*   cursor   = (int*)alloc((size_t)n * sizeof(int));
    int*   srcSorted= (int*)alloc((size_t)e * sizeof(int));
    (void)ws_size; (void)n_in; (void)out_size;

    hipMemsetAsync(counts, 0, (size_t)n * sizeof(int), stream);
    hipMemsetAsync(cursor, 0, (size_t)n * sizeof(int), stream);

    qkv_gemm<<<(n + GEMM_BN - 1) / GEMM_BN, 256, 0, stream>>>(
        h, Wq, bq, Wk, bk, Wv, bv, Q, K, V, n);

    hist_kernel<<<(e + 255) / 256, 256, 0, stream>>>(dst, counts, e);
    scan_block_sums<<<nb, 256, 0, stream>>>(counts, bsums, n);
    scan_exclusive_small<<<1, 256, 0, stream>>>(bsums, nb);
    scan_final<<<nb, 256, 0, stream>>>(counts, bsums, offsets, n, e);
    fill_kernel<<<(e + 255) / 256, 256, 0, stream>>>(src, dst, offsets, cursor, srcSorted, e);

    const int groups = n * 8;
    mha_edge<<<(groups + 15) / 16, 256, 0, stream>>>(Q, K, V, offsets, srcSorted, out, n);
}

// Round 2
// 294.801 us; speedup vs baseline: 1.2630x; 1.2630x over previous
//
#include <hip/hip_runtime.h>
#include <hip/hip_bf16.h>

// IN_DIM=128, H=8, D=16, H*D=128.

#define GEMM_BN 64

// ---------------------------------------------------------------------------
// Fused QKV GEMM: Y = h @ W + b, fp32 vector ALU.
// Output pointers carry an explicit row stride so K and V can be interleaved
// into a combined KV[n][256] buffer (K in cols 0..127, V in cols 128..255).
// ---------------------------------------------------------------------------
__global__ __launch_bounds__(256) void qkv_gemm(
    const float* __restrict__ h,
    const float* __restrict__ W0, const float* __restrict__ b0,
    const float* __restrict__ W1, const float* __restrict__ b1,
    const float* __restrict__ W2, const float* __restrict__ b2,
    float* __restrict__ Y0, int ls0,
    float* __restrict__ Y1, int ls1,
    float* __restrict__ Y2, int ls2,
    int n)
{
    __shared__ float hT[128][GEMM_BN];  // [k][row]
    __shared__ float wS[128][64];       // [k][col]

    const int tid  = threadIdx.x;
    const int row0 = blockIdx.x * GEMM_BN;

    {
        const int r = tid & 63, kq = tid >> 6;
        const int row = row0 + r;
        if (row < n) {
            const float* hp = h + (size_t)row * 128 + kq * 32;
#pragma unroll
            for (int j = 0; j < 8; ++j) {
                float4 v = *(const float4*)(hp + j * 4);
                int k = kq * 32 + j * 4;
                hT[k + 0][r] = v.x; hT[k + 1][r] = v.y;
                hT[k + 2][r] = v.z; hT[k + 3][r] = v.w;
            }
        } else {
#pragma unroll
            for (int j = 0; j < 8; ++j) {
                int k = kq * 32 + j * 4;
                hT[k + 0][r] = 0.f; hT[k + 1][r] = 0.f;
                hT[k + 2][r] = 0.f; hT[k + 3][r] = 0.f;
            }
        }
    }

    const float* Ws[3] = {W0, W1, W2};
    const float* bs[3] = {b0, b1, b2};
    float*       Ys[3] = {Y0, Y1, Y2};
    const int    lss[3] = {ls0, ls1, ls2};

    const int tc = tid & 15;
    const int tr = tid >> 4;

    for (int w = 0; w < 3; ++w) {
        for (int ch = 0; ch < 2; ++ch) {
            __syncthreads();
            for (int t = tid; t < 128 * 16; t += 256) {
                int k = t >> 4, c4 = (t & 15) * 4;
                *(float4*)&wS[k][c4] =
                    *(const float4*)(Ws[w] + (size_t)k * 128 + ch * 64 + c4);
            }
            __syncthreads();

            float acc[4][4];
            float4 bvv = *(const float4*)(bs[w] + ch * 64 + tc * 4);
#pragma unroll
            for (int i = 0; i < 4; ++i) {
                acc[i][0] = bvv.x; acc[i][1] = bvv.y;
                acc[i][2] = bvv.z; acc[i][3] = bvv.w;
            }

#pragma unroll 8
            for (int k = 0; k < 128; ++k) {
                float4 a = *(const float4*)&hT[k][tr * 4];
                float4 b = *(const float4*)&wS[k][tc * 4];
                float ar[4] = {a.x, a.y, a.z, a.w};
                float br[4] = {b.x, b.y, b.z, b.w};
#pragma unroll
                for (int i = 0; i < 4; ++i)
#pragma unroll
                    for (int j = 0; j < 4; ++j)
                        acc[i][j] = fmaf(ar[i], br[j], acc[i][j]);
            }

            float* Y = Ys[w];
            const int ls = lss[w];
#pragma unroll
            for (int i = 0; i < 4; ++i) {
                int row = row0 + tr * 4 + i;
                if (row < n) {
                    *(float4*)(Y + (size_t)row * ls + ch * 64 + tc * 4) =
                        make_float4(acc[i][0], acc[i][1], acc[i][2], acc[i][3]);
                }
            }
        }
    }
}

// ---------------------------------------------------------------------------
// CSR build: histogram -> hierarchical exclusive scan -> fill
// ---------------------------------------------------------------------------
__global__ void hist_kernel(const int* __restrict__ dst, int* __restrict__ counts, int e) {
    int i = blockIdx.x * blockDim.x + threadIdx.x;
    if (i < e) atomicAdd(&counts[dst[i]], 1);
}

__global__ void scan_block_sums(const int* __restrict__ counts, int* __restrict__ bsums, int nelem) {
    __shared__ int red[4];
    int i = blockIdx.x * 256 + threadIdx.x;
    int v = (i < nelem) ? counts[i] : 0;
#pragma unroll
    for (int o = 32; o > 0; o >>= 1) v += __shfl_down(v, o, 64);
    if ((threadIdx.x & 63) == 0) red[threadIdx.x >> 6] = v;
    __syncthreads();
    if (threadIdx.x == 0) bsums[blockIdx.x] = red[0] + red[1] + red[2] + red[3];
}

__global__ void scan_exclusive_small(int* __restrict__ bsums, int nb) {
    __shared__ int tmp[256];
    int t = threadIdx.x;
    int v = (t < nb) ? bsums[t] : 0;
    tmp[t] = v;
    __syncthreads();
    for (int o = 1; o < 256; o <<= 1) {
        int u = (t >= o) ? tmp[t - o] : 0;
        __syncthreads();
        tmp[t] += u;
        __syncthreads();
    }
    if (t < nb) bsums[t] = tmp[t] - v;  // exclusive
}

__global__ void scan_final(const int* __restrict__ counts, const int* __restrict__ bsums,
                           int* __restrict__ offsets, int nelem, int e) {
    __shared__ int tmp[256];
    int t = threadIdx.x;
    int i = blockIdx.x * 256 + t;
    int v = (i < nelem) ? counts[i] : 0;
    tmp[t] = v;
    __syncthreads();
    for (int o = 1; o < 256; o <<= 1) {
        int u = (t >= o) ? tmp[t - o] : 0;
        __syncthreads();
        tmp[t] += u;
        __syncthreads();
    }
    if (i < nelem) offsets[i] = bsums[blockIdx.x] + tmp[t] - v;
    if (i == 0 && blockIdx.x == 0) offsets[nelem] = e;
}

__global__ void fill_kernel(const int* __restrict__ src, const int* __restrict__ dst,
                            const int* __restrict__ offsets, int* __restrict__ cursor,
                            int* __restrict__ srcSorted, int e) {
    int i = blockIdx.x * blockDim.x + threadIdx.x;
    if (i < e) {
        int d = dst[i];
        int pos = offsets[d] + atomicAdd(&cursor[d], 1);
        srcSorted[pos] = src[i];
    }
}

// ---------------------------------------------------------------------------
// Gather: ONE 64-lane wave per node, all 8 heads together.
// Lane l owns output dims {2l, 2l+1}; head = l>>3 (8 lanes per head).
// KV rows are 256 floats: K in [0,128), V in [128,256) -> one edge touches
// one contiguous 1KB row via two 512B wave loads.
// Scores clamped to [-5,5] before softmax => exp in [6.7e-3,148.4]; the
// segment-max shift is unnecessary (softmax shift-invariance).
// ---------------------------------------------------------------------------
__global__ __launch_bounds__(256) void mha_node(
    const float* __restrict__ Q, const float* __restrict__ KV,
    const int* __restrict__ offsets, const int* __restrict__ srcSorted,
    float* __restrict__ out, int n)
{
    const int lane = threadIdx.x & 63;
    const int node = (blockIdx.x * blockDim.x + threadIdx.x) >> 6;
    if (node >= n) return;

    const float2 q = *(const float2*)(Q + (size_t)node * 128 + lane * 2);
    const int beg = offsets[node], end = offsets[node + 1];

    float accx = 0.f, accy = 0.f, lsum = 0.f;

    for (int j0 = beg; j0 < end; j0 += 64) {
        const int rem = end - j0;
        const int cnt = rem < 64 ? rem : 64;
        int myS = (lane < cnt) ? srcSorted[j0 + lane] : 0;

        int t = 0;
        for (; t + 4 <= cnt; t += 4) {
            int s0 = __shfl(myS, t + 0);
            int s1 = __shfl(myS, t + 1);
            int s2 = __shfl(myS, t + 2);
            int s3 = __shfl(myS, t + 3);
            const float2* p0 = (const float2*)(KV + (size_t)s0 * 256) + lane;
            const float2* p1 = (const float2*)(KV + (size_t)s1 * 256) + lane;
            const float2* p2 = (const float2*)(KV + (size_t)s2 * 256) + lane;
            const float2* p3 = (const float2*)(KV + (size_t)s3 * 256) + lane;
            float2 k0 = p0[0], v0 = p0[64];
            float2 k1 = p1[0], v1 = p1[64];
            float2 k2 = p2[0], v2 = p2[64];
            float2 k3 = p3[0], v3 = p3[64];

#define EDGE_COMPUTE(kk, vv)                                        \
            {                                                       \
                float prod = fmaf(kk.x, q.x, kk.y * q.y);           \
                prod += __shfl_xor(prod, 1);                        \
                prod += __shfl_xor(prod, 2);                        \
                prod += __shfl_xor(prod, 4);                        \
                float sc = fminf(5.f, fmaxf(-5.f, prod * 0.25f));   \
                float p = __expf(sc);                               \
                lsum += p;                                          \
                accx = fmaf(p, vv.x, accx);                         \
                accy = fmaf(p, vv.y, accy);                         \
            }

            EDGE_COMPUTE(k0, v0)
            EDGE_COMPUTE(k1, v1)
            EDGE_COMPUTE(k2, v2)
            EDGE_COMPUTE(k3, v3)
        }
        for (; t < cnt; ++t) {
            int s0 = __shfl(myS, t);
            const float2* p0 = (const float2*)(KV + (size_t)s0 * 256) + lane;
            float2 k0 = p0[0], v0 = p0[64];
            EDGE_COMPUTE(k0, v0)
        }
    }

    float inv = (lsum > 0.f) ? 1.f / lsum : 0.f;
    *(float2*)(out + (size_t)node * 128 + lane * 2) =
        make_float2(accx * inv, accy * inv);
}

// ---------------------------------------------------------------------------
extern "C" void kernel_launch(void* const* d_in, const int* in_sizes, int n_in,
                              void* d_out, int out_size, void* d_ws, size_t ws_size,
                              hipStream_t stream) {
    const float* h  = (const float*)d_in[0];
    const float* Wq = (const float*)d_in[1];
    const float* bq = (const float*)d_in[2];
    const float* Wk = (const float*)d_in[3];
    const float* bk = (const float*)d_in[4];
    const float* Wv = (const float*)d_in[5];
    const float* bv = (const float*)d_in[6];
    const int*   src = (const int*)d_in[7];
    const int*   dst = (const int*)d_in[8];
    float* out = (float*)d_out;

    const int n = in_sizes[0] / 128;
    const int e = in_sizes[7];
    const int nb = (n + 255) / 256;  // must be <= 256 (n=50000 -> 196)

    char* ws = (char*)d_ws;
    size_t off = 0;
    auto alloc = [&](size_t bytes) {
        char* p = ws + off;
        off = (off + bytes + 255) & ~(size_t)255;
        return p;
    };
    float* Q        = (float*)alloc((size_t)n * 128 * sizeof(float));
    float* KV       = (float*)alloc((size_t)n * 256 * sizeof(float));
    int*   counts   = (int*)alloc((size_t)n * sizeof(int));
    int*   offsets  = (int*)alloc((size_t)(n + 1) * sizeof(int));
    int*   bsums    = (int*)alloc((size_t)nb * sizeof(int));
    int*   cursor   = (int*)alloc((size_t)n * sizeof(int));
    int*   srcSorted= (int*)alloc((size_t)e * sizeof(int));
    (void)ws_size; (void)n_in; (void)out_size;

    hipMemsetAsync(counts, 0, (size_t)n * sizeof(int), stream);
    hipMemsetAsync(cursor, 0, (size_t)n * sizeof(int), stream);

    qkv_gemm<<<(n + GEMM_BN - 1) / GEMM_BN, 256, 0, stream>>>(
        h, Wq, bq, Wk, bk, Wv, bv,
        Q, 128,          // Q rows of 128
        KV, 256,         // K -> KV cols 0..127
        KV + 128, 256,   // V -> KV cols 128..255
        n);

    hist_kernel<<<(e + 255) / 256, 256, 0, stream>>>(dst, counts, e);
    scan_block_sums<<<nb, 256, 0, stream>>>(counts, bsums, n);
    scan_exclusive_small<<<1, 256, 0, stream>>>(bsums, nb);
    scan_final<<<nb, 256, 0, stream>>>(counts, bsums, offsets, n, e);
    fill_kernel<<<(e + 255) / 256, 256, 0, stream>>>(src, dst, offsets, cursor, srcSorted, e);

    mha_node<<<((size_t)n * 64 + 255) / 256, 256, 0, stream>>>(
        Q, KV, offsets, srcSorted, out, n);
}

// Round 3
// 245.239 us; speedup vs baseline: 1.5182x; 1.2021x over previous
//
#include <hip/hip_runtime.h>
#include <hip/hip_bf16.h>

// IN_DIM=128, H=8, D=16, H*D=128.

#define GEMM_BN 64

__device__ __forceinline__ unsigned pack_bf16(float a, float b) {
    unsigned ua = __float_as_uint(a), ub = __float_as_uint(b);
    ua += 0x7fffu + ((ua >> 16) & 1u);          // RNE round to bf16
    ub += 0x7fffu + ((ub >> 16) & 1u);
    return (ua >> 16) | (ub & 0xffff0000u);
}

// ---------------------------------------------------------------------------
// Fused QKV GEMM: Y = h @ W + b, fp32 vector ALU.
// Q written fp32 [n][128]. K,V packed bf16 into KV[n][64] uint2 rows:
// lane l's uint2 = { bf16x2 K[2l..2l+1], bf16x2 V[2l..2l+1] } -> one edge is
// a single contiguous 512B row read by one wave-wide 8B/lane load.
// As uint array: K pair (c,c+1) at index row*128 + c; V pair at row*128+c+1.
// ---------------------------------------------------------------------------
__global__ __launch_bounds__(256) void qkv_gemm(
    const float* __restrict__ h,
    const float* __restrict__ W0, const float* __restrict__ b0,
    const float* __restrict__ W1, const float* __restrict__ b1,
    const float* __restrict__ W2, const float* __restrict__ b2,
    float* __restrict__ Qout, unsigned* __restrict__ kvU,
    int n)
{
    __shared__ float hT[128][GEMM_BN];  // [k][row]
    __shared__ float wS[128][64];       // [k][col]

    const int tid  = threadIdx.x;
    const int row0 = blockIdx.x * GEMM_BN;

    {
        const int r = tid & 63, kq = tid >> 6;
        const int row = row0 + r;
        if (row < n) {
            const float* hp = h + (size_t)row * 128 + kq * 32;
#pragma unroll
            for (int j = 0; j < 8; ++j) {
                float4 v = *(const float4*)(hp + j * 4);
                int k = kq * 32 + j * 4;
                hT[k + 0][r] = v.x; hT[k + 1][r] = v.y;
                hT[k + 2][r] = v.z; hT[k + 3][r] = v.w;
            }
        } else {
#pragma unroll
            for (int j = 0; j < 8; ++j) {
                int k = kq * 32 + j * 4;
                hT[k + 0][r] = 0.f; hT[k + 1][r] = 0.f;
                hT[k + 2][r] = 0.f; hT[k + 3][r] = 0.f;
            }
        }
    }

    const float* Ws[3] = {W0, W1, W2};
    const float* bs[3] = {b0, b1, b2};

    const int tc = tid & 15;
    const int tr = tid >> 4;

    for (int w = 0; w < 3; ++w) {
        for (int ch = 0; ch < 2; ++ch) {
            __syncthreads();
            for (int t = tid; t < 128 * 16; t += 256) {
                int k = t >> 4, c4 = (t & 15) * 4;
                *(float4*)&wS[k][c4] =
                    *(const float4*)(Ws[w] + (size_t)k * 128 + ch * 64 + c4);
            }
            __syncthreads();

            float acc[4][4];
            float4 bvv = *(const float4*)(bs[w] + ch * 64 + tc * 4);
#pragma unroll
            for (int i = 0; i < 4; ++i) {
                acc[i][0] = bvv.x; acc[i][1] = bvv.y;
                acc[i][2] = bvv.z; acc[i][3] = bvv.w;
            }

#pragma unroll 8
            for (int k = 0; k < 128; ++k) {
                float4 a = *(const float4*)&hT[k][tr * 4];
                float4 b = *(const float4*)&wS[k][tc * 4];
                float ar[4] = {a.x, a.y, a.z, a.w};
                float br[4] = {b.x, b.y, b.z, b.w};
#pragma unroll
                for (int i = 0; i < 4; ++i)
#pragma unroll
                    for (int j = 0; j < 4; ++j)
                        acc[i][j] = fmaf(ar[i], br[j], acc[i][j]);
            }

            const int c = ch * 64 + tc * 4;   // global output col (c%4==0)
#pragma unroll
            for (int i = 0; i < 4; ++i) {
                int row = row0 + tr * 4 + i;
                if (row >= n) continue;
                if (w == 0) {
                    *(float4*)(Qout + (size_t)row * 128 + c) =
                        make_float4(acc[i][0], acc[i][1], acc[i][2], acc[i][3]);
                } else {
                    const int par = (w == 1) ? 0 : 1;   // K even, V odd
                    unsigned* p = kvU + (size_t)row * 128 + c + par;
                    p[0] = pack_bf16(acc[i][0], acc[i][1]);
                    p[2] = pack_bf16(acc[i][2], acc[i][3]);
                }
            }
        }
    }
}

// ---------------------------------------------------------------------------
// CSR build: histogram -> hierarchical exclusive scan -> fill
// ---------------------------------------------------------------------------
__global__ void hist_kernel(const int* __restrict__ dst, int* __restrict__ counts, int e) {
    int i = blockIdx.x * blockDim.x + threadIdx.x;
    if (i < e) atomicAdd(&counts[dst[i]], 1);
}

__global__ void scan_block_sums(const int* __restrict__ counts, int* __restrict__ bsums, int nelem) {
    __shared__ int red[4];
    int i = blockIdx.x * 256 + threadIdx.x;
    int v = (i < nelem) ? counts[i] : 0;
#pragma unroll
    for (int o = 32; o > 0; o >>= 1) v += __shfl_down(v, o, 64);
    if ((threadIdx.x & 63) == 0) red[threadIdx.x >> 6] = v;
    __syncthreads();
    if (threadIdx.x == 0) bsums[blockIdx.x] = red[0] + red[1] + red[2] + red[3];
}

__global__ void scan_exclusive_small(int* __restrict__ bsums, int nb) {
    __shared__ int tmp[256];
    int t = threadIdx.x;
    int v = (t < nb) ? bsums[t] : 0;
    tmp[t] = v;
    __syncthreads();
    for (int o = 1; o < 256; o <<= 1) {
        int u = (t >= o) ? tmp[t - o] : 0;
        __syncthreads();
        tmp[t] += u;
        __syncthreads();
    }
    if (t < nb) bsums[t] = tmp[t] - v;  // exclusive
}

__global__ void scan_final(const int* __restrict__ counts, const int* __restrict__ bsums,
                           int* __restrict__ offsets, int nelem, int e) {
    __shared__ int tmp[256];
    int t = threadIdx.x;
    int i = blockIdx.x * 256 + t;
    int v = (i < nelem) ? counts[i] : 0;
    tmp[t] = v;
    __syncthreads();
    for (int o = 1; o < 256; o <<= 1) {
        int u = (t >= o) ? tmp[t - o] : 0;
        __syncthreads();
        tmp[t] += u;
        __syncthreads();
    }
    if (i < nelem) offsets[i] = bsums[blockIdx.x] + tmp[t] - v;
    if (i == 0 && blockIdx.x == 0) offsets[nelem] = e;
}

__global__ void fill_kernel(const int* __restrict__ src, const int* __restrict__ dst,
                            const int* __restrict__ offsets, int* __restrict__ cursor,
                            int* __restrict__ srcSorted, int e) {
    int i = blockIdx.x * blockDim.x + threadIdx.x;
    if (i < e) {
        int d = dst[i];
        int pos = offsets[d] + atomicAdd(&cursor[d], 1);
        srcSorted[pos] = src[i];
    }
}

// ---------------------------------------------------------------------------
// Gather: one 64-lane wave per node, all 8 heads. Lane l owns dims {2l,2l+1};
// head = l>>3. KV row = 64 uint2 (512B, bf16-packed). Scores clamped to
// [-5,5] before softmax -> exp in [6.7e-3,148.4]; segment-max shift is
// unnecessary (softmax shift-invariance).
// ---------------------------------------------------------------------------
__global__ __launch_bounds__(256) void mha_node(
    const float* __restrict__ Q, const uint2* __restrict__ KV,
    const int* __restrict__ offsets, const int* __restrict__ srcSorted,
    float* __restrict__ out, int n)
{
    const int lane = threadIdx.x & 63;
    const int node = (blockIdx.x * blockDim.x + threadIdx.x) >> 6;
    if (node >= n) return;

    const float2 q = *(const float2*)(Q + (size_t)node * 128 + lane * 2);
    const int beg = offsets[node], end = offsets[node + 1];

    float accx = 0.f, accy = 0.f, lsum = 0.f;

#define EDGE_COMPUTE(kv)                                              \
    {                                                                 \
        float kx = __uint_as_float((kv).x << 16);                     \
        float ky = __uint_as_float((kv).x & 0xffff0000u);             \
        float prod = fmaf(kx, q.x, ky * q.y);                         \
        prod += __shfl_xor(prod, 1);                                  \
        prod += __shfl_xor(prod, 2);                                  \
        prod += __shfl_xor(prod, 4);                                  \
        float sc = fminf(5.f, fmaxf(-5.f, prod * 0.25f));             \
        float p = __expf(sc);                                         \
        lsum += p;                                                    \
        accx = fmaf(p, __uint_as_float((kv).y << 16), accx);          \
        accy = fmaf(p, __uint_as_float((kv).y & 0xffff0000u), accy);  \
    }

    for (int j0 = beg; j0 < end; j0 += 64) {
        const int rem = end - j0;
        const int cnt = rem < 64 ? rem : 64;
        int myS = (lane < cnt) ? srcSorted[j0 + lane] : 0;

        int t = 0;
        for (; t + 8 <= cnt; t += 8) {
            uint2 kv[8];
#pragma unroll
            for (int u = 0; u < 8; ++u) {
                int s = __shfl(myS, t + u);
                kv[u] = KV[(size_t)s * 64 + lane];
            }
#pragma unroll
            for (int u = 0; u < 8; ++u) EDGE_COMPUTE(kv[u]);
        }
        for (; t < cnt; ++t) {
            int s = __shfl(myS, t);
            uint2 kv0 = KV[(size_t)s * 64 + lane];
            EDGE_COMPUTE(kv0);
        }
    }

    float inv = (lsum > 0.f) ? 1.f / lsum : 0.f;
    *(float2*)(out + (size_t)node * 128 + lane * 2) =
        make_float2(accx * inv, accy * inv);
}

// ---------------------------------------------------------------------------
extern "C" void kernel_launch(void* const* d_in, const int* in_sizes, int n_in,
                              void* d_out, int out_size, void* d_ws, size_t ws_size,
                              hipStream_t stream) {
    const float* h  = (const float*)d_in[0];
    const float* Wq = (const float*)d_in[1];
    const float* bq = (const float*)d_in[2];
    const float* Wk = (const float*)d_in[3];
    const float* bk = (const float*)d_in[4];
    const float* Wv = (const float*)d_in[5];
    const float* bv = (const float*)d_in[6];
    const int*   src = (const int*)d_in[7];
    const int*   dst = (const int*)d_in[8];
    float* out = (float*)d_out;

    const int n = in_sizes[0] / 128;
    const int e = in_sizes[7];
    const int nb = (n + 255) / 256;  // must be <= 256 (n=50000 -> 196)

    char* ws = (char*)d_ws;
    size_t off = 0;
    auto alloc = [&](size_t bytes) {
        char* p = ws + off;
        off = (off + bytes + 255) & ~(size_t)255;
        return p;
    };
    float*    Q        = (float*)alloc((size_t)n * 128 * sizeof(float));
    unsigned* KVb      = (unsigned*)alloc((size_t)n * 128 * sizeof(unsigned));
    int*      counts   = (int*)alloc((size_t)n * sizeof(int));
    int*      offsets  = (int*)alloc((size_t)(n + 1) * sizeof(int));
    int*      bsums    = (int*)alloc((size_t)nb * sizeof(int));
    int*      cursor   = (int*)alloc((size_t)n * sizeof(int));
    int*      srcSorted= (int*)alloc((size_t)e * sizeof(int));
    (void)ws_size; (void)n_in; (void)out_size;

    hipMemsetAsync(counts, 0, (size_t)n * sizeof(int), stream);
    hipMemsetAsync(cursor, 0, (size_t)n * sizeof(int), stream);

    qkv_gemm<<<(n + GEMM_BN - 1) / GEMM_BN, 256, 0, stream>>>(
        h, Wq, bq, Wk, bk, Wv, bv, Q, KVb, n);

    hist_kernel<<<(e + 255) / 256, 256, 0, stream>>>(dst, counts, e);
    scan_block_sums<<<nb, 256, 0, stream>>>(counts, bsums, n);
    scan_exclusive_small<<<1, 256, 0, stream>>>(bsums, nb);
    scan_final<<<nb, 256, 0, stream>>>(counts, bsums, offsets, n, e);
    fill_kernel<<<(e + 255) / 256, 256, 0, stream>>>(src, dst, offsets, cursor, srcSorted, e);

    mha_node<<<((size_t)n * 64 + 255) / 256, 256, 0, stream>>>(
        (const float*)Q, (const uint2*)KVb, offsets, srcSorted, out, n);
}

// Round 4
// 191.695 us; speedup vs baseline: 1.9423x; 1.2793x over previous
//
#include <hip/hip_runtime.h>
#include <hip/hip_bf16.h>

// IN_DIM=128, H=8, D=16, H*D=128.

typedef short short8 __attribute__((ext_vector_type(8)));
typedef float f32x4 __attribute__((ext_vector_type(4)));

__device__ __forceinline__ unsigned pack_bf16(float a, float b) {
    unsigned ua = __float_as_uint(a), ub = __float_as_uint(b);
    ua += 0x7fffu + ((ua >> 16) & 1u);          // RNE round to bf16
    ub += 0x7fffu + ((ub >> 16) & 1u);
    return (ua >> 16) | (ub & 0xffff0000u);
}

// ---------------------------------------------------------------------------
// MFMA QKV GEMM. BM=128 rows/block, 256 threads = 4 waves (2x2), each wave a
// 64x64 tile = 4x4 frags of mfma_f32_16x16x32_bf16. h and WT staged as bf16
// in LDS with the (row&7)<<4 XOR swizzle. Ws processed sequentially.
// Outputs: Q fp32 [n][128]; K,V packed bf16 into kvU: uint idx row*128 + c
// holds cols (c,c+1) of K when c even (+1 -> V), matching mha_node's uint2
// per-lane layout.
// ---------------------------------------------------------------------------
__global__ __launch_bounds__(256) void qkv_gemm_mfma(
    const float* __restrict__ h,
    const float* __restrict__ W0, const float* __restrict__ b0,
    const float* __restrict__ W1, const float* __restrict__ b1,
    const float* __restrict__ W2, const float* __restrict__ b2,
    float* __restrict__ Qout, unsigned* __restrict__ kvU, int n)
{
    __shared__ __align__(16) unsigned char lds[65536];  // [0,32K): h  [32K,64K): WT
    const int tid  = threadIdx.x;
    const int row0 = blockIdx.x * 128;

    // ---- stage h tile: fp32 -> bf16, swizzled rows of 256B ----
    for (int idx = tid; idx < 128 * 32; idx += 256) {
        const int row = idx >> 5;
        const int c4  = (idx & 31) * 4;
        float4 v = make_float4(0.f, 0.f, 0.f, 0.f);
        if (row0 + row < n)
            v = *(const float4*)(h + (size_t)(row0 + row) * 128 + c4);
        const unsigned off = row * 256 + ((c4 * 2) ^ ((row & 7) << 4));
        *(uint2*)(lds + off) = make_uint2(pack_bf16(v.x, v.y), pack_bf16(v.z, v.w));
    }

    const float* Ws[3] = {W0, W1, W2};
    const float* bs[3] = {b0, b1, b2};

    const int lane = tid & 63, wave = tid >> 6;
    const int wr = wave >> 1, wc = wave & 1;
    const int lr = lane & 15, lg = lane >> 4;
    const int rot = tid & 3;

    for (int w = 0; w < 3; ++w) {
        __syncthreads();   // prev k-loop done with WT; (iter 0) h-stage done
        // ---- stage WT[col][k] bf16 swizzled (transpose of W) ----
        for (int idx = tid; idx < 64 * 32; idx += 256) {
            const int kp = idx >> 5;              // k-pair (2kp, 2kp+1)
            const int c4 = (idx & 31) * 4;
            const float* Wp = Ws[w] + (size_t)(2 * kp) * 128 + c4;
            float4 wa = *(const float4*)Wp;
            float4 wb = *(const float4*)(Wp + 128);
            float a0[4] = {wa.x, wa.y, wa.z, wa.w};
            float a1[4] = {wb.x, wb.y, wb.z, wb.w};
#pragma unroll
            for (int j = 0; j < 4; ++j) {
                const int i   = (j + rot) & 3;    // rotate write order: avoid 16-way bank conflict
                const int col = c4 + i;
                const unsigned off = 32768u + col * 256 + ((4 * kp) ^ ((col & 7) << 4));
                *(unsigned*)(lds + off) = pack_bf16(a0[i], a1[i]);
            }
        }
        __syncthreads();

        // ---- MFMA k-loop: wave (wr,wc) computes 64x64 ----
        f32x4 acc[4][4];
#pragma unroll
        for (int nt = 0; nt < 4; ++nt) {
            const float bv = bs[w][wc * 64 + nt * 16 + lr];
#pragma unroll
            for (int mt = 0; mt < 4; ++mt)
                acc[mt][nt] = (f32x4){bv, bv, bv, bv};
        }
#pragma unroll
        for (int ks = 0; ks < 4; ++ks) {
            const int kb = ks * 64 + lg * 16;     // byte offset of 8 bf16
            short8 af[4], bf[4];
#pragma unroll
            for (int mt = 0; mt < 4; ++mt) {
                const int row = wr * 64 + mt * 16 + lr;
                af[mt] = *(const short8*)(lds + row * 256 + (kb ^ ((row & 7) << 4)));
            }
#pragma unroll
            for (int nt = 0; nt < 4; ++nt) {
                const int col = wc * 64 + nt * 16 + lr;
                bf[nt] = *(const short8*)(lds + 32768u + col * 256 + (kb ^ ((col & 7) << 4)));
            }
#pragma unroll
            for (int mt = 0; mt < 4; ++mt)
#pragma unroll
                for (int nt = 0; nt < 4; ++nt)
                    acc[mt][nt] = __builtin_amdgcn_mfma_f32_16x16x32_bf16(
                        af[mt], bf[nt], acc[mt][nt], 0, 0, 0);
        }

        // ---- epilogue: pair adjacent cols via shfl_xor(1) ----
#pragma unroll
        for (int mt = 0; mt < 4; ++mt) {
#pragma unroll
            for (int nt = 0; nt < 4; ++nt) {
                const int col = wc * 64 + nt * 16 + lr;
#pragma unroll
                for (int r = 0; r < 4; ++r) {
                    const int row = row0 + wr * 64 + mt * 16 + lg * 4 + r;
                    const float v  = acc[mt][nt][r];
                    const float vn = __shfl_xor(v, 1);
                    if (!(lane & 1) && row < n) {
                        if (w == 0) {
                            *(float2*)(Qout + (size_t)row * 128 + col) = make_float2(v, vn);
                        } else {
                            kvU[(size_t)row * 128 + col + (w - 1)] = pack_bf16(v, vn);
                        }
                    }
                }
            }
        }
    }
}

// ---------------------------------------------------------------------------
// CSR build: histogram -> hierarchical exclusive scan -> fill
// ---------------------------------------------------------------------------
__global__ void hist_kernel(const int* __restrict__ dst, int* __restrict__ counts, int e) {
    int i = blockIdx.x * blockDim.x + threadIdx.x;
    if (i < e) atomicAdd(&counts[dst[i]], 1);
}

__global__ void scan_block_sums(const int* __restrict__ counts, int* __restrict__ bsums, int nelem) {
    __shared__ int red[4];
    int i = blockIdx.x * 256 + threadIdx.x;
    int v = (i < nelem) ? counts[i] : 0;
#pragma unroll
    for (int o = 32; o > 0; o >>= 1) v += __shfl_down(v, o, 64);
    if ((threadIdx.x & 63) == 0) red[threadIdx.x >> 6] = v;
    __syncthreads();
    if (threadIdx.x == 0) bsums[blockIdx.x] = red[0] + red[1] + red[2] + red[3];
}

__global__ void scan_exclusive_small(int* __restrict__ bsums, int nb) {
    __shared__ int tmp[256];
    int t = threadIdx.x;
    int v = (t < nb) ? bsums[t] : 0;
    tmp[t] = v;
    __syncthreads();
    for (int o = 1; o < 256; o <<= 1) {
        int u = (t >= o) ? tmp[t - o] : 0;
        __syncthreads();
        tmp[t] += u;
        __syncthreads();
    }
    if (t < nb) bsums[t] = tmp[t] - v;  // exclusive
}

__global__ void scan_final(const int* __restrict__ counts, const int* __restrict__ bsums,
                           int* __restrict__ offsets, int nelem, int e) {
    __shared__ int tmp[256];
    int t = threadIdx.x;
    int i = blockIdx.x * 256 + t;
    int v = (i < nelem) ? counts[i] : 0;
    tmp[t] = v;
    __syncthreads();
    for (int o = 1; o < 256; o <<= 1) {
        int u = (t >= o) ? tmp[t - o] : 0;
        __syncthreads();
        tmp[t] += u;
        __syncthreads();
    }
    if (i < nelem) offsets[i] = bsums[blockIdx.x] + tmp[t] - v;
    if (i == 0 && blockIdx.x == 0) offsets[nelem] = e;
}

__global__ void fill_kernel(const int* __restrict__ src, const int* __restrict__ dst,
                            const int* __restrict__ offsets, int* __restrict__ cursor,
                            int* __restrict__ srcSorted, int e) {
    int i = blockIdx.x * blockDim.x + threadIdx.x;
    if (i < e) {
        int d = dst[i];
        int pos = offsets[d] + atomicAdd(&cursor[d], 1);
        srcSorted[pos] = src[i];
    }
}

// ---------------------------------------------------------------------------
// Gather: one 64-lane wave per node, all 8 heads. Lane l owns dims {2l,2l+1};
// head = l>>3. KV row = 64 uint2 (512B, bf16-packed). Scores clamped to
// [-5,5] before softmax -> exp in [6.7e-3,148.4]; segment-max shift is
// unnecessary (softmax shift-invariance).
// ---------------------------------------------------------------------------
__global__ __launch_bounds__(256) void mha_node(
    const float* __restrict__ Q, const uint2* __restrict__ KV,
    const int* __restrict__ offsets, const int* __restrict__ srcSorted,
    float* __restrict__ out, int n)
{
    const int lane = threadIdx.x & 63;
    const int node = (blockIdx.x * blockDim.x + threadIdx.x) >> 6;
    if (node >= n) return;

    const float2 q = *(const float2*)(Q + (size_t)node * 128 + lane * 2);
    const int beg = offsets[node], end = offsets[node + 1];

    float accx = 0.f, accy = 0.f, lsum = 0.f;

#define EDGE_COMPUTE(kv)                                              \
    {                                                                 \
        float kx = __uint_as_float((kv).x << 16);                     \
        float ky = __uint_as_float((kv).x & 0xffff0000u);             \
        float prod = fmaf(kx, q.x, ky * q.y);                         \
        prod += __shfl_xor(prod, 1);                                  \
        prod += __shfl_xor(prod, 2);                                  \
        prod += __shfl_xor(prod, 4);                                  \
        float sc = fminf(5.f, fmaxf(-5.f, prod * 0.25f));             \
        float p = __expf(sc);                                         \
        lsum += p;                                                    \
        accx = fmaf(p, __uint_as_float((kv).y << 16), accx);          \
        accy = fmaf(p, __uint_as_float((kv).y & 0xffff0000u), accy);  \
    }

    for (int j0 = beg; j0 < end; j0 += 64) {
        const int rem = end - j0;
        const int cnt = rem < 64 ? rem : 64;
        int myS = (lane < cnt) ? srcSorted[j0 + lane] : 0;

        int t = 0;
        for (; t + 8 <= cnt; t += 8) {
            uint2 kv[8];
#pragma unroll
            for (int u = 0; u < 8; ++u) {
                int s = __shfl(myS, t + u);
                kv[u] = KV[(size_t)s * 64 + lane];
            }
#pragma unroll
            for (int u = 0; u < 8; ++u) EDGE_COMPUTE(kv[u]);
        }
        for (; t < cnt; ++t) {
            int s = __shfl(myS, t);
            uint2 kv0 = KV[(size_t)s * 64 + lane];
            EDGE_COMPUTE(kv0);
        }
    }

    float inv = (lsum > 0.f) ? 1.f / lsum : 0.f;
    *(float2*)(out + (size_t)node * 128 + lane * 2) =
        make_float2(accx * inv, accy * inv);
}

// ---------------------------------------------------------------------------
extern "C" void kernel_launch(void* const* d_in, const int* in_sizes, int n_in,
                              void* d_out, int out_size, void* d_ws, size_t ws_size,
                              hipStream_t stream) {
    const float* h  = (const float*)d_in[0];
    const float* Wq = (const float*)d_in[1];
    const float* bq = (const float*)d_in[2];
    const float* Wk = (const float*)d_in[3];
    const float* bk = (const float*)d_in[4];
    const float* Wv = (const float*)d_in[5];
    const float* bv = (const float*)d_in[6];
    const int*   src = (const int*)d_in[7];
    const int*   dst = (const int*)d_in[8];
    float* out = (float*)d_out;

    const int n = in_sizes[0] / 128;
    const int e = in_sizes[7];
    const int nb = (n + 255) / 256;  // must be <= 256 (n=50000 -> 196)

    char* ws = (char*)d_ws;
    size_t off = 0;
    auto alloc = [&](size_t bytes) {
        char* p = ws + off;
        off = (off + bytes + 255) & ~(size_t)255;
        return p;
    };
    float*    Q        = (float*)alloc((size_t)n * 128 * sizeof(float));
    unsigned* KVb      = (unsigned*)alloc((size_t)n * 128 * sizeof(unsigned));
    int*      counts   = (int*)alloc((size_t)n * sizeof(int));
    int*      offsets  = (int*)alloc((size_t)(n + 1) * sizeof(int));
    int*      bsums    = (int*)alloc((size_t)nb * sizeof(int));
    int*      cursor   = (int*)alloc((size_t)n * sizeof(int));
    int*      srcSorted= (int*)alloc((size_t)e * sizeof(int));
    (void)ws_size; (void)n_in; (void)out_size;

    hipMemsetAsync(counts, 0, (size_t)n * sizeof(int), stream);
    hipMemsetAsync(cursor, 0, (size_t)n * sizeof(int), stream);

    qkv_gemm_mfma<<<(n + 127) / 128, 256, 0, stream>>>(
        h, Wq, bq, Wk, bk, Wv, bv, Q, KVb, n);

    hist_kernel<<<(e + 255) / 256, 256, 0, stream>>>(dst, counts, e);
    scan_block_sums<<<nb, 256, 0, stream>>>(counts, bsums, n);
    scan_exclusive_small<<<1, 256, 0, stream>>>(bsums, nb);
    scan_final<<<nb, 256, 0, stream>>>(counts, bsums, offsets, n, e);
    fill_kernel<<<(e + 255) / 256, 256, 0, stream>>>(src, dst, offsets, cursor, srcSorted, e);

    mha_node<<<((size_t)n * 64 + 255) / 256, 256, 0, stream>>>(
        (const float*)Q, (const uint2*)KVb, offsets, srcSorted, out, n);
}